// Round 2
// baseline (7194.695 us; speedup 1.0000x reference)
//
#include <hip/hip_runtime.h>

// Problem constants (reference: N=32768, M=8192, D=64, fp32)
#define N_ROWS 32768
#define M_COLS 8192
#define D_DIM  64
#define JC     8      // j-chunks (grid.y) -> partial mins
#define TJ     128    // y rows staged per LDS tile (128*64*4B = 32 KB)
#define BLOCK  256
#define ROWS_PER_BLOCK 256  // 1 row per thread (64 VGPRs of x, NO spill)

// ---------- kernel 1: t[j] = ||y_j||^2 - psi[j] ----------
__global__ void prep_t_kernel(const float* __restrict__ y,
                              const float* __restrict__ psi,
                              float* __restrict__ t) {
    int j = blockIdx.x * blockDim.x + threadIdx.x;
    if (j >= M_COLS) return;
    const float4* yr = reinterpret_cast<const float4*>(y + (size_t)j * D_DIM);
    float s = 0.f;
#pragma unroll
    for (int k = 0; k < D_DIM / 4; ++k) {
        float4 v = yr[k];
        s += v.x * v.x + v.y * v.y + v.z * v.z + v.w * v.w;
    }
    t[j] = s - psi[j];
}

// ---------- kernel 2: partial min over a j-chunk ----------
// part[jc*N + i] = x2[i] + min_{j in chunk} (t[j] - 2*<x_i, y_j>)
// 1 x-row per thread held in registers; y broadcast from LDS (conflict-free).
__global__ __launch_bounds__(BLOCK, 4) void partial_min_kernel(
    const float* __restrict__ x, const float* __restrict__ y,
    const float* __restrict__ t, float* __restrict__ part) {
    __shared__ float4 sY[TJ * (D_DIM / 4)];
    __shared__ float  sT[TJ];

    const int tid = threadIdx.x;
    const int rb  = blockIdx.x;   // row block [0,128)
    const int jc  = blockIdx.y;   // j chunk  [0,JC)

    const int i0 = rb * ROWS_PER_BLOCK + tid;

    // load 1 x-row into registers (64 VGPRs), compute ||x||^2 on the fly
    float4 xr[D_DIM / 4];
    const float4* p0 = reinterpret_cast<const float4*>(x + (size_t)i0 * D_DIM);
    float x20 = 0.f;
#pragma unroll
    for (int k = 0; k < D_DIM / 4; ++k) {
        xr[k] = p0[k];
        x20 += xr[k].x * xr[k].x + xr[k].y * xr[k].y +
               xr[k].z * xr[k].z + xr[k].w * xr[k].w;
    }

    float m0 = INFINITY;
    const int jbase  = jc * (M_COLS / JC);
    const int ntiles = (M_COLS / JC) / TJ;  // 1024/128 = 8

    for (int tile = 0; tile < ntiles; ++tile) {
        const int jt = jbase + tile * TJ;
        __syncthreads();  // protect previous tile from overwrite
        // stage y tile: 2048 float4, 256 threads -> 8 each, coalesced
        const float4* ysrc = reinterpret_cast<const float4*>(y + (size_t)jt * D_DIM);
#pragma unroll
        for (int k = 0; k < (TJ * D_DIM / 4) / BLOCK; ++k)
            sY[tid + k * BLOCK] = ysrc[tid + k * BLOCK];
        if (tid < TJ) sT[tid] = t[jt + tid];
        __syncthreads();

#pragma unroll 2
        for (int jj = 0; jj < TJ; ++jj) {
            // 4 independent accumulator chains for ILP
            float a0 = 0.f, a1 = 0.f, a2 = 0.f, a3 = 0.f;
#pragma unroll
            for (int k = 0; k < D_DIM / 4; k += 4) {
                float4 y0 = sY[jj * (D_DIM / 4) + k + 0];
                float4 y1 = sY[jj * (D_DIM / 4) + k + 1];
                float4 y2 = sY[jj * (D_DIM / 4) + k + 2];
                float4 y3 = sY[jj * (D_DIM / 4) + k + 3];
                a0 += xr[k+0].x * y0.x + xr[k+0].y * y0.y +
                      xr[k+0].z * y0.z + xr[k+0].w * y0.w;
                a1 += xr[k+1].x * y1.x + xr[k+1].y * y1.y +
                      xr[k+1].z * y1.z + xr[k+1].w * y1.w;
                a2 += xr[k+2].x * y2.x + xr[k+2].y * y2.y +
                      xr[k+2].z * y2.z + xr[k+2].w * y2.w;
                a3 += xr[k+3].x * y3.x + xr[k+3].y * y3.y +
                      xr[k+3].z * y3.z + xr[k+3].w * y3.w;
            }
            const float a = (a0 + a1) + (a2 + a3);
            m0 = fminf(m0, fmaf(-2.f, a, sT[jj]));
        }
    }
    part[(size_t)jc * N_ROWS + i0] = m0 + x20;
}

// ---------- kernel 3: per-row min over chunks, partial row-sum per block ----------
__global__ __launch_bounds__(BLOCK) void row_reduce_kernel(
    const float* __restrict__ part, float* __restrict__ bsum) {
    const int tid = threadIdx.x;
    float s = 0.f;
#pragma unroll
    for (int r = 0; r < 2; ++r) {
        const int i = blockIdx.x * 512 + r * 256 + tid;
        float m = part[i];
#pragma unroll
        for (int c = 1; c < JC; ++c)
            m = fminf(m, part[(size_t)c * N_ROWS + i]);
        s += m;
    }
    // wave reduce (64 lanes)
    for (int off = 32; off > 0; off >>= 1) s += __shfl_down(s, off, 64);
    __shared__ float tmp[4];
    const int lane = tid & 63, wave = tid >> 6;
    if (lane == 0) tmp[wave] = s;
    __syncthreads();
    if (tid == 0) bsum[blockIdx.x] = tmp[0] + tmp[1] + tmp[2] + tmp[3];
}

// ---------- kernel 4: final scalar ----------
__global__ __launch_bounds__(BLOCK) void final_kernel(
    const float* __restrict__ bsum, const float* __restrict__ psi,
    float* __restrict__ out) {
    const int tid = threadIdx.x;
    float s = (tid < 64) ? bsum[tid] : 0.f;
    float p = 0.f;
    for (int j = tid; j < M_COLS; j += BLOCK) p += psi[j];
    for (int off = 32; off > 0; off >>= 1) {
        s += __shfl_down(s, off, 64);
        p += __shfl_down(p, off, 64);
    }
    __shared__ float ts[4], tp[4];
    const int lane = tid & 63, wave = tid >> 6;
    if (lane == 0) { ts[wave] = s; tp[wave] = p; }
    __syncthreads();
    if (tid == 0) {
        float S = ts[0] + ts[1] + ts[2] + ts[3];
        float P = tp[0] + tp[1] + tp[2] + tp[3];
        out[0] = S / (float)N_ROWS + P / (float)M_COLS;
    }
}

extern "C" void kernel_launch(void* const* d_in, const int* in_sizes, int n_in,
                              void* d_out, int out_size, void* d_ws, size_t ws_size,
                              hipStream_t stream) {
    const float* x   = (const float*)d_in[0];   // [N,D]
    const float* y   = (const float*)d_in[1];   // [M,D]
    const float* psi = (const float*)d_in[2];   // [M]
    float* out = (float*)d_out;

    // workspace layout
    float* part = (float*)d_ws;                          // JC*N floats = 1 MB
    float* t    = part + (size_t)JC * N_ROWS;            // M floats
    float* bsum = t + M_COLS;                            // 64 floats

    prep_t_kernel<<<M_COLS / BLOCK, BLOCK, 0, stream>>>(y, psi, t);
    partial_min_kernel<<<dim3(N_ROWS / ROWS_PER_BLOCK, JC), BLOCK, 0, stream>>>(x, y, t, part);
    row_reduce_kernel<<<N_ROWS / 512, BLOCK, 0, stream>>>(part, bsum);
    final_kernel<<<1, BLOCK, 0, stream>>>(bsum, psi, out);
}

// Round 3
// 147.376 us; speedup vs baseline: 48.8187x; 48.8187x over previous
//
#include <hip/hip_runtime.h>

// Problem constants (reference: N=32768, M=8192, D=64, fp32)
#define N_ROWS 32768
#define M_COLS 8192
#define D_DIM  64
#define JC     8                      // j-chunks (grid.y) -> partial mins
#define BLOCK  256
#define ROWS_PER_BLOCK 256            // 4 waves x 64 rows
#define SUBT   ((M_COLS / JC) / 16)   // 64 subtiles of 16 j per chunk

typedef _Float16 v8h __attribute__((ext_vector_type(8)));
typedef _Float16 v4h __attribute__((ext_vector_type(4)));
typedef float    v4f __attribute__((ext_vector_type(4)));

// ---------- kernel 1: yh = (half)y, t[j] = ||y_j||^2 - psi[j] ----------
// block handles 16 rows; 16 threads per row, 4 elements each (coalesced).
__global__ __launch_bounds__(BLOCK) void prep_kernel(
    const float* __restrict__ y, const float* __restrict__ psi,
    _Float16* __restrict__ yh, float* __restrict__ t) {
    const int tid = threadIdx.x;
    const int j = blockIdx.x * 16 + (tid >> 4);  // row
    const int n = tid & 15;                      // 4-elem segment
    const float4 v = *(const float4*)(y + (size_t)j * D_DIM + n * 4);
    float s = v.x * v.x + v.y * v.y + v.z * v.z + v.w * v.w;
    v4h hv = { (_Float16)v.x, (_Float16)v.y, (_Float16)v.z, (_Float16)v.w };
    *(v4h*)(yh + (size_t)j * D_DIM + n * 4) = hv;  // 8B store, contiguous
    // reduce sumsq across the 16 lanes of this row (lane bits 0..3)
#pragma unroll
    for (int m = 1; m < 16; m <<= 1) s += __shfl_xor(s, m, 64);
    if (n == 0) t[j] = s - psi[j];
}

// ---------- kernel 2: MFMA partial min over a j-chunk ----------
// part[jc*N + i] = min_{j in chunk} (t[j] - 2*<x_i, y_j>)   (x2 added later)
__global__ __launch_bounds__(BLOCK) void partial_min_kernel(
    const float* __restrict__ x, const _Float16* __restrict__ yh,
    const float* __restrict__ t, float* __restrict__ part) {
    const int tid  = threadIdx.x;
    const int lane = tid & 63, wave = tid >> 6;
    const int q = lane >> 4, n = lane & 15;
    const int jc    = blockIdx.y;
    const int jbase = jc * (M_COLS / JC);
    const int i_wave = blockIdx.x * ROWS_PER_BLOCK + wave * 64;

    // A-frags: 4 row-groups x 2 k-chunks, loaded once from fp32 x, cvt to f16.
    // A layout (16x16x32): m = lane&15, k = quad*8 + idx  [verified m120]
    v8h a[4][2];
#pragma unroll
    for (int g = 0; g < 4; ++g) {
        const float* px = x + (size_t)(i_wave + g * 16 + n) * D_DIM + q * 8;
#pragma unroll
        for (int c = 0; c < 2; ++c) {
            float4 f0 = *(const float4*)(px + c * 32);
            float4 f1 = *(const float4*)(px + c * 32 + 4);
            v8h av = { (_Float16)f0.x, (_Float16)f0.y, (_Float16)f0.z, (_Float16)f0.w,
                       (_Float16)f1.x, (_Float16)f1.y, (_Float16)f1.z, (_Float16)f1.w };
            a[g][c] = av;
        }
    }

    float mins[4][4];
#pragma unroll
    for (int g = 0; g < 4; ++g)
#pragma unroll
        for (int r = 0; r < 4; ++r) mins[g][r] = INFINITY;

    // B-frag base: row j = jbase + s*16 + n, k = quad*8 + c*32 (8 halves = 16B)
    const v8h* pb = (const v8h*)yh + ((size_t)(jbase + n) * 8 + q);
    const float* pt = t + jbase + n;

#pragma unroll 2
    for (int s = 0; s < SUBT; ++s) {
        const float tv = pt[s * 16];
        const v8h b0 = pb[(size_t)s * 128];      // c=0
        const v8h b1 = pb[(size_t)s * 128 + 4];  // c=1 (+32 halves)
#pragma unroll
        for (int g = 0; g < 4; ++g) {
            v4f acc = { 0.f, 0.f, 0.f, 0.f };
            acc = __builtin_amdgcn_mfma_f32_16x16x32_f16(a[g][0], b0, acc, 0, 0, 0);
            acc = __builtin_amdgcn_mfma_f32_16x16x32_f16(a[g][1], b1, acc, 0, 0, 0);
            // C/D: col(j) = lane&15 = n, row(i) = quad*4 + r  [verified m89]
#pragma unroll
            for (int r = 0; r < 4; ++r)
                mins[g][r] = fminf(mins[g][r], fmaf(-2.f, acc[r], tv));
        }
    }

    // reduce mins across the 16 j-phase lanes (lane bits 0..3), then store
#pragma unroll
    for (int g = 0; g < 4; ++g) {
#pragma unroll
        for (int r = 0; r < 4; ++r) {
            float v = mins[g][r];
#pragma unroll
            for (int m = 1; m < 16; m <<= 1)
                v = fminf(v, __shfl_xor(v, m, 64));
            if (n == 0)
                part[(size_t)jc * N_ROWS + i_wave + g * 16 + q * 4 + r] = v;
        }
    }
}

// ---------- kernel 3: per-row min over chunks + x2, partial row-sum ----------
__global__ __launch_bounds__(BLOCK) void row_reduce_kernel(
    const float* __restrict__ part, const float* __restrict__ x,
    float* __restrict__ bsum) {
    const int tid = threadIdx.x;
    float s = 0.f;
#pragma unroll
    for (int rr = 0; rr < 2; ++rr) {
        const int i = blockIdx.x * 512 + rr * 256 + tid;
        float m = part[i];
#pragma unroll
        for (int c = 1; c < JC; ++c)
            m = fminf(m, part[(size_t)c * N_ROWS + i]);
        const float4* px = (const float4*)(x + (size_t)i * D_DIM);
        float x2 = 0.f;
#pragma unroll
        for (int k = 0; k < D_DIM / 4; ++k) {
            float4 v = px[k];
            x2 += v.x * v.x + v.y * v.y + v.z * v.z + v.w * v.w;
        }
        s += m + x2;
    }
    for (int off = 32; off > 0; off >>= 1) s += __shfl_down(s, off, 64);
    __shared__ float tmp[4];
    const int lane = tid & 63, wave = tid >> 6;
    if (lane == 0) tmp[wave] = s;
    __syncthreads();
    if (tid == 0) bsum[blockIdx.x] = tmp[0] + tmp[1] + tmp[2] + tmp[3];
}

// ---------- kernel 4: final scalar ----------
__global__ __launch_bounds__(BLOCK) void final_kernel(
    const float* __restrict__ bsum, const float* __restrict__ psi,
    float* __restrict__ out) {
    const int tid = threadIdx.x;
    float s = (tid < 64) ? bsum[tid] : 0.f;
    float p = 0.f;
    for (int j = tid; j < M_COLS; j += BLOCK) p += psi[j];
    for (int off = 32; off > 0; off >>= 1) {
        s += __shfl_down(s, off, 64);
        p += __shfl_down(p, off, 64);
    }
    __shared__ float ts[4], tp[4];
    const int lane = tid & 63, wave = tid >> 6;
    if (lane == 0) { ts[wave] = s; tp[wave] = p; }
    __syncthreads();
    if (tid == 0) {
        float S = ts[0] + ts[1] + ts[2] + ts[3];
        float P = tp[0] + tp[1] + tp[2] + tp[3];
        out[0] = S / (float)N_ROWS + P / (float)M_COLS;
    }
}

extern "C" void kernel_launch(void* const* d_in, const int* in_sizes, int n_in,
                              void* d_out, int out_size, void* d_ws, size_t ws_size,
                              hipStream_t stream) {
    const float* x   = (const float*)d_in[0];   // [N,D]
    const float* y   = (const float*)d_in[1];   // [M,D]
    const float* psi = (const float*)d_in[2];   // [M]
    float* out = (float*)d_out;

    // workspace layout
    float* part = (float*)d_ws;                       // JC*N floats = 1 MB
    float* t    = part + (size_t)JC * N_ROWS;         // M floats
    float* bsum = t + M_COLS;                         // 64 floats
    _Float16* yh = (_Float16*)(bsum + 64);            // M*D halves = 1 MB (16B-aligned)

    prep_kernel<<<M_COLS / 16, BLOCK, 0, stream>>>(y, psi, yh, t);
    partial_min_kernel<<<dim3(N_ROWS / ROWS_PER_BLOCK, JC), BLOCK, 0, stream>>>(x, yh, t, part);
    row_reduce_kernel<<<N_ROWS / 512, BLOCK, 0, stream>>>(part, x, bsum);
    final_kernel<<<1, BLOCK, 0, stream>>>(bsum, psi, out);
}